// Round 1
// baseline (7003.952 us; speedup 1.0000x reference)
//
#include <hip/hip_runtime.h>
#include <hip/hip_bf16.h>

#define TE 32
#define EPSV 1e-8f

__device__ __forceinline__ float silu_f(float x) {
    return x / (1.0f + __expf(-x));
}

// acc[4e][4o] += in[e0..e0+3][0..K) @ W[0..K)[o0..o0+3]   (W row-major K x 128)
__device__ __forceinline__ void gemm4x4(const float* __restrict__ Wg,
                                        const float* a0p, const float* a1p,
                                        const float* a2p, const float* a3p,
                                        int K, int o0, float acc[4][4]) {
    for (int k = 0; k < K; k += 4) {
        float4 a0 = *(const float4*)(a0p + k);
        float4 a1 = *(const float4*)(a1p + k);
        float4 a2 = *(const float4*)(a2p + k);
        float4 a3 = *(const float4*)(a3p + k);
        float4 w0 = *(const float4*)(Wg + (k + 0) * 128 + o0);
        float4 w1 = *(const float4*)(Wg + (k + 1) * 128 + o0);
        float4 w2 = *(const float4*)(Wg + (k + 2) * 128 + o0);
        float4 w3 = *(const float4*)(Wg + (k + 3) * 128 + o0);
        float av[4][4] = {{a0.x, a0.y, a0.z, a0.w},
                          {a1.x, a1.y, a1.z, a1.w},
                          {a2.x, a2.y, a2.z, a2.w},
                          {a3.x, a3.y, a3.z, a3.w}};
        float wv[4][4] = {{w0.x, w0.y, w0.z, w0.w},
                          {w1.x, w1.y, w1.z, w1.w},
                          {w2.x, w2.y, w2.z, w2.w},
                          {w3.x, w3.y, w3.z, w3.w}};
        #pragma unroll
        for (int i = 0; i < 4; ++i)
            #pragma unroll
            for (int kk = 0; kk < 4; ++kk)
                #pragma unroll
                for (int j = 0; j < 4; ++j)
                    acc[i][j] = fmaf(av[i][kk], wv[kk][j], acc[i][j]);
    }
}

__device__ __forceinline__ void zero4x4(float acc[4][4]) {
    #pragma unroll
    for (int i = 0; i < 4; ++i)
        #pragma unroll
        for (int j = 0; j < 4; ++j) acc[i][j] = 0.f;
}

// ---------------- embed: h = h_in @ emb_W + emb_b  (N x 64) @ (64 x 128)
__global__ __launch_bounds__(256) void embed_kernel(
    const float* __restrict__ hin, const float* __restrict__ W,
    const float* __restrict__ b, float* __restrict__ hbuf, int N)
{
    __shared__ float in_tile[TE][68];
    const int t = threadIdx.x;
    const int nb = blockIdx.x * TE;

    #pragma unroll
    for (int it = 0; it < 2; ++it) {
        int flat = t + 256 * it;          // 0..511 : 32 nodes x 16 float4
        int c = flat & 15;
        int e = flat >> 4;
        int node = nb + e; if (node >= N) node = N - 1;
        *(float4*)(&in_tile[e][c * 4]) = *(const float4*)(hin + (size_t)node * 64 + c * 4);
    }
    __syncthreads();

    const int o0 = (t & 31) * 4;
    const int e0 = (t >> 5) * 4;
    float acc[4][4];
    zero4x4(acc);
    gemm4x4(W, &in_tile[e0][0], &in_tile[e0 + 1][0], &in_tile[e0 + 2][0], &in_tile[e0 + 3][0],
            64, o0, acc);
    float4 bv = *(const float4*)(b + o0);
    #pragma unroll
    for (int i = 0; i < 4; ++i) {
        int node = nb + e0 + i;
        if (node < N) {
            float4 v = make_float4(acc[i][0] + bv.x, acc[i][1] + bv.y,
                                   acc[i][2] + bv.z, acc[i][3] + bv.w);
            *(float4*)(&hbuf[(size_t)node * 128 + o0]) = v;
        }
    }
}

// ---------------- per-layer edge kernel: messages + coord weights, scatter-add
__global__ __launch_bounds__(256) void edge_kernel(
    const float* __restrict__ hbuf, const float* __restrict__ posb,
    const int* __restrict__ ei,
    const float* __restrict__ W1, const float* __restrict__ b1,
    const float* __restrict__ W2, const float* __restrict__ b2,
    const float* __restrict__ cW1, const float* __restrict__ cb1,
    const float* __restrict__ cW2, const float* __restrict__ cb2,
    float* __restrict__ agg, float* __restrict__ pdel,
    int E, int N)
{
    const int Etot = E + N;
    __shared__ float in_tile[TE][260];   // [hi(128) | hj(128) | dist(1)]
    __shared__ float m1s[TE][132];
    __shared__ int   srcl[TE], dstl[TE];
    __shared__ float relt[3][TE];
    __shared__ float distl[TE], wscl[TE];
    __shared__ float red[TE][8];

    const int t = threadIdx.x;
    const int eb = blockIdx.x * TE;

    if (t < TE) {
        int e = eb + t;
        int s = 0, d = 0;
        if (e < E)          { s = ei[e]; d = ei[E + e]; }
        else if (e < Etot)  { s = d = e - E; }
        srcl[t] = s; dstl[t] = d;
        float rx = posb[3 * s + 0] - posb[3 * d + 0];
        float ry = posb[3 * s + 1] - posb[3 * d + 1];
        float rz = posb[3 * s + 2] - posb[3 * d + 2];
        float dist = sqrtf(rx * rx + ry * ry + rz * rz);
        relt[0][t] = rx; relt[1][t] = ry; relt[2][t] = rz;
        distl[t] = dist;
        in_tile[t][256] = dist;
    }
    __syncthreads();

    // gather h[dst] -> cols 0..127, h[src] -> cols 128..255
    #pragma unroll
    for (int it = 0; it < 8; ++it) {
        int flat = t + 256 * it;          // 0..2047 : 64 rows x 32 float4
        int c = flat & 31;
        int row = flat >> 5;
        int e = row >> 1, half = row & 1;
        int node = half ? srcl[e] : dstl[e];
        float4 v = *(const float4*)(hbuf + (size_t)node * 128 + c * 4);
        *(float4*)(&in_tile[e][half * 128 + c * 4]) = v;
    }
    __syncthreads();

    const int o0 = (t & 31) * 4;
    const int e0 = (t >> 5) * 4;
    float acc[4][4];

    // m1 = silu(in @ W1 + b1), K = 257
    zero4x4(acc);
    gemm4x4(W1, &in_tile[e0][0], &in_tile[e0 + 1][0], &in_tile[e0 + 2][0], &in_tile[e0 + 3][0],
            256, o0, acc);
    #pragma unroll
    for (int i = 0; i < 4; ++i) {           // K tail: k = 256 (dist)
        float dv = in_tile[e0 + i][256];
        #pragma unroll
        for (int j = 0; j < 4; ++j)
            acc[i][j] = fmaf(dv, W1[256 * 128 + o0 + j], acc[i][j]);
    }
    {
        float4 bv = *(const float4*)(b1 + o0);
        #pragma unroll
        for (int i = 0; i < 4; ++i) {
            float4 v = make_float4(silu_f(acc[i][0] + bv.x), silu_f(acc[i][1] + bv.y),
                                   silu_f(acc[i][2] + bv.z), silu_f(acc[i][3] + bv.w));
            *(float4*)(&m1s[e0 + i][o0]) = v;
        }
    }
    __syncthreads();

    // m2 = silu(m1 @ W2 + b2) -> atomicAdd into agg[dst]
    zero4x4(acc);
    gemm4x4(W2, &m1s[e0][0], &m1s[e0 + 1][0], &m1s[e0 + 2][0], &m1s[e0 + 3][0],
            128, o0, acc);
    {
        float4 bv = *(const float4*)(b2 + o0);
        #pragma unroll
        for (int i = 0; i < 4; ++i) {
            int ge = eb + e0 + i;
            if (ge < Etot) {
                float* ap = agg + (size_t)dstl[e0 + i] * 128 + o0;
                atomicAdd(ap + 0, silu_f(acc[i][0] + bv.x));
                atomicAdd(ap + 1, silu_f(acc[i][1] + bv.y));
                atomicAdd(ap + 2, silu_f(acc[i][2] + bv.z));
                atomicAdd(ap + 3, silu_f(acc[i][3] + bv.w));
            }
        }
    }
    __syncthreads();   // all m1s reads done before overwrite

    // c1 = silu(hj @ cW1 + cb1) -> m1s (reuse)
    zero4x4(acc);
    gemm4x4(cW1, &in_tile[e0][128], &in_tile[e0 + 1][128], &in_tile[e0 + 2][128],
            &in_tile[e0 + 3][128], 128, o0, acc);
    {
        float4 bv = *(const float4*)(cb1 + o0);
        #pragma unroll
        for (int i = 0; i < 4; ++i) {
            float4 v = make_float4(silu_f(acc[i][0] + bv.x), silu_f(acc[i][1] + bv.y),
                                   silu_f(acc[i][2] + bv.z), silu_f(acc[i][3] + bv.w));
            *(float4*)(&m1s[e0 + i][o0]) = v;
        }
    }
    __syncthreads();

    // w[e] = c1[e] . cW2 + cb2 ;  scale = w/(dist+eps)
    {
        int e = t >> 3, g = t & 7;
        float s = 0.f;
        #pragma unroll
        for (int m = 0; m < 16; ++m) {
            int k = g * 16 + m;
            s = fmaf(m1s[e][k], cW2[k], s);
        }
        red[e][g] = s;
    }
    __syncthreads();
    if (t < TE) {
        float s = 0.f;
        #pragma unroll
        for (int g = 0; g < 8; ++g) s += red[t][g];
        s += cb2[0];
        wscl[t] = s / (distl[t] + EPSV);
    }
    __syncthreads();
    if (t < 3 * TE) {
        int e = t / 3, comp = t % 3;
        int ge = eb + e;
        if (ge < Etot) {
            atomicAdd(&pdel[(size_t)dstl[e] * 3 + comp], wscl[e] * relt[comp][e]);
        }
    }
}

// ---------------- per-layer node update: h += MLP([h,agg]); pos += pdel
__global__ __launch_bounds__(256) void node_kernel(
    float* __restrict__ hbuf, const float* __restrict__ agg,
    float* __restrict__ posb, const float* __restrict__ pdel,
    const float* __restrict__ W1, const float* __restrict__ b1,
    const float* __restrict__ W2, const float* __restrict__ b2,
    int N)
{
    __shared__ float in_tile[TE][260];   // [h(128) | agg(128)]
    __shared__ float us[TE][132];
    const int t = threadIdx.x;
    const int nb = blockIdx.x * TE;

    #pragma unroll
    for (int it = 0; it < 8; ++it) {
        int flat = t + 256 * it;
        int c = flat & 31;
        int row = flat >> 5;
        int e = row >> 1, half = row & 1;
        int node = nb + e; if (node >= N) node = N - 1;
        const float* src = half ? (agg + (size_t)node * 128) : (hbuf + (size_t)node * 128);
        *(float4*)(&in_tile[e][half * 128 + c * 4]) = *(const float4*)(src + c * 4);
    }
    __syncthreads();

    const int o0 = (t & 31) * 4;
    const int e0 = (t >> 5) * 4;
    float acc[4][4];

    zero4x4(acc);
    gemm4x4(W1, &in_tile[e0][0], &in_tile[e0 + 1][0], &in_tile[e0 + 2][0], &in_tile[e0 + 3][0],
            256, o0, acc);
    {
        float4 bv = *(const float4*)(b1 + o0);
        #pragma unroll
        for (int i = 0; i < 4; ++i) {
            float4 v = make_float4(silu_f(acc[i][0] + bv.x), silu_f(acc[i][1] + bv.y),
                                   silu_f(acc[i][2] + bv.z), silu_f(acc[i][3] + bv.w));
            *(float4*)(&us[e0 + i][o0]) = v;
        }
    }
    __syncthreads();

    zero4x4(acc);
    gemm4x4(W2, &us[e0][0], &us[e0 + 1][0], &us[e0 + 2][0], &us[e0 + 3][0],
            128, o0, acc);
    {
        float4 bv = *(const float4*)(b2 + o0);
        #pragma unroll
        for (int i = 0; i < 4; ++i) {
            int node = nb + e0 + i;
            if (node < N) {
                float4 v = make_float4(in_tile[e0 + i][o0 + 0] + acc[i][0] + bv.x,
                                       in_tile[e0 + i][o0 + 1] + acc[i][1] + bv.y,
                                       in_tile[e0 + i][o0 + 2] + acc[i][2] + bv.z,
                                       in_tile[e0 + i][o0 + 3] + acc[i][3] + bv.w);
                *(float4*)(&hbuf[(size_t)node * 128 + o0]) = v;
            }
        }
    }
    if (t < 3 * TE) {
        int e = t / 3, comp = t % 3;
        int node = nb + e;
        if (node < N) posb[3 * node + comp] += pdel[3 * node + comp];
    }
}

// ---------------- output head: out = silu(h@W1+b1)@W2 + b2
__global__ __launch_bounds__(256) void out_kernel(
    const float* __restrict__ hbuf,
    const float* __restrict__ W1, const float* __restrict__ b1,
    const float* __restrict__ W2, const float* __restrict__ b2,
    float* __restrict__ outp, int N)
{
    __shared__ float in_tile[TE][132];
    __shared__ float us[TE][132];
    const int t = threadIdx.x;
    const int nb = blockIdx.x * TE;

    #pragma unroll
    for (int it = 0; it < 4; ++it) {
        int flat = t + 256 * it;          // 0..1023 : 32 nodes x 32 float4
        int c = flat & 31;
        int e = flat >> 5;
        int node = nb + e; if (node >= N) node = N - 1;
        *(float4*)(&in_tile[e][c * 4]) = *(const float4*)(hbuf + (size_t)node * 128 + c * 4);
    }
    __syncthreads();

    const int o0 = (t & 31) * 4;
    const int e0 = (t >> 5) * 4;
    float acc[4][4];

    zero4x4(acc);
    gemm4x4(W1, &in_tile[e0][0], &in_tile[e0 + 1][0], &in_tile[e0 + 2][0], &in_tile[e0 + 3][0],
            128, o0, acc);
    {
        float4 bv = *(const float4*)(b1 + o0);
        #pragma unroll
        for (int i = 0; i < 4; ++i) {
            float4 v = make_float4(silu_f(acc[i][0] + bv.x), silu_f(acc[i][1] + bv.y),
                                   silu_f(acc[i][2] + bv.z), silu_f(acc[i][3] + bv.w));
            *(float4*)(&us[e0 + i][o0]) = v;
        }
    }
    __syncthreads();

    zero4x4(acc);
    gemm4x4(W2, &us[e0][0], &us[e0 + 1][0], &us[e0 + 2][0], &us[e0 + 3][0],
            128, o0, acc);
    {
        float4 bv = *(const float4*)(b2 + o0);
        #pragma unroll
        for (int i = 0; i < 4; ++i) {
            int node = nb + e0 + i;
            if (node < N) {
                float4 v = make_float4(acc[i][0] + bv.x, acc[i][1] + bv.y,
                                       acc[i][2] + bv.z, acc[i][3] + bv.w);
                *(float4*)(&outp[(size_t)node * 128 + o0]) = v;
            }
        }
    }
}

extern "C" void kernel_launch(void* const* d_in, const int* in_sizes, int n_in,
                              void* d_out, int out_size, void* d_ws, size_t ws_size,
                              hipStream_t stream)
{
    const float* hin  = (const float*)d_in[0];
    const float* pos  = (const float*)d_in[1];
    const int*   ei   = (const int*)d_in[2];
    const float* embW = (const float*)d_in[3];
    const float* embb = (const float*)d_in[4];
    const float* mW1  = (const float*)d_in[5];
    const float* mb1  = (const float*)d_in[6];
    const float* mW2  = (const float*)d_in[7];
    const float* mb2  = (const float*)d_in[8];
    const float* cW1  = (const float*)d_in[9];
    const float* cb1  = (const float*)d_in[10];
    const float* cW2  = (const float*)d_in[11];
    const float* cb2  = (const float*)d_in[12];
    const float* nW1  = (const float*)d_in[13];
    const float* nb1  = (const float*)d_in[14];
    const float* nW2  = (const float*)d_in[15];
    const float* nb2  = (const float*)d_in[16];
    const float* oW1  = (const float*)d_in[17];
    const float* ob1  = (const float*)d_in[18];
    const float* oW2  = (const float*)d_in[19];
    const float* ob2  = (const float*)d_in[20];

    const int N = in_sizes[0] / 64;
    const int E = in_sizes[2] / 2;
    const int Etot = E + N;

    float* hbuf = (float*)d_ws;                       // N*128
    float* aggb = hbuf + (size_t)N * 128;             // N*128
    float* posb = aggb + (size_t)N * 128;             // N*3
    float* pdel = posb + (size_t)N * 3;               // N*3
    float* outp = (float*)d_out;

    hipMemcpyAsync(posb, pos, (size_t)N * 3 * sizeof(float),
                   hipMemcpyDeviceToDevice, stream);

    const int nodeBlocks = (N + TE - 1) / TE;
    const int edgeBlocks = (Etot + TE - 1) / TE;

    embed_kernel<<<nodeBlocks, 256, 0, stream>>>(hin, embW, embb, hbuf, N);

    for (int l = 0; l < 4; ++l) {
        hipMemsetAsync(aggb, 0, (size_t)N * 128 * sizeof(float), stream);
        hipMemsetAsync(pdel, 0, (size_t)N * 3 * sizeof(float), stream);
        edge_kernel<<<edgeBlocks, 256, 0, stream>>>(
            hbuf, posb, ei,
            mW1 + (size_t)l * 257 * 128, mb1 + l * 128,
            mW2 + (size_t)l * 128 * 128, mb2 + l * 128,
            cW1 + (size_t)l * 128 * 128, cb1 + l * 128,
            cW2 + (size_t)l * 128,       cb2 + l,
            aggb, pdel, E, N);
        node_kernel<<<nodeBlocks, 256, 0, stream>>>(
            hbuf, aggb, posb, pdel,
            nW1 + (size_t)l * 256 * 128, nb1 + l * 128,
            nW2 + (size_t)l * 128 * 128, nb2 + l * 128, N);
    }
    out_kernel<<<nodeBlocks, 256, 0, stream>>>(hbuf, oW1, ob1, oW2, ob2, outp, N);

    hipMemcpyAsync(outp + (size_t)N * 128, posb, (size_t)N * 3 * sizeof(float),
                   hipMemcpyDeviceToDevice, stream);
}

// Round 2
// 2238.278 us; speedup vs baseline: 3.1292x; 3.1292x over previous
//
#include <hip/hip_runtime.h>
#include <hip/hip_bf16.h>

#define EPSV 1e-8f

typedef short bf16x8 __attribute__((ext_vector_type(8)));
typedef float f32x4  __attribute__((ext_vector_type(4)));

__device__ __forceinline__ float silu_f(float x) {
    return x / (1.0f + __expf(-x));
}

// ======================= weight repack: f32 KxN(row-major, N=128) -> bf16 MFMA-B frags
// packed[chunk c][group g][col n][j] = W[c*32+g*8+j][n], chunk = 32 K-rows = 4096 bf16
#define MAXM 24
struct PackArgs {
    const float* src[MAXM];
    unsigned int doff[MAXM];   // dst offset in bf16 elems
    int nchunk[MAXM];
    int nmat;
};

__global__ __launch_bounds__(256) void repack_kernel(PackArgs pa, __hip_bfloat16* base)
{
    int bid = blockIdx.x;
    int m = 0, c = bid;
    while (m < pa.nmat && c >= pa.nchunk[m]) { c -= pa.nchunk[m]; ++m; }
    const float* src = pa.src[m];
    __hip_bfloat16* dst = base + pa.doff[m] + (size_t)c * 4096;
    for (int o = threadIdx.x; o < 4096; o += 256) {
        int j = o & 7, n = (o >> 3) & 127, g = o >> 10;
        dst[o] = __float2bfloat16(src[(size_t)(c * 32 + g * 8 + j) * 128 + n]);
    }
}

// ======================= core MFMA tile GEMM
// C[64][32(cols w*32..)] += A[64][K] @ B ; A in LDS (bf16, row-stride LDA),
// B packed in global. Wave w does all 64 rows x its 32 cols. acc[rowtile][coltile]
template<int LDA>
__device__ __forceinline__ void mfma_gemm(const __hip_bfloat16 (*At)[LDA], int acol0,
                                          const __hip_bfloat16* __restrict__ Bp,
                                          int kchunks, int w, int lane, f32x4 acc[4][2])
{
    const int ar = lane & 15, g = lane >> 4;
    const int bc = w * 32 + (lane & 15);
    for (int c = 0; c < kchunks; ++c) {
        const int ao = acol0 + c * 32 + g * 8;
        bf16x8 a0 = *(const bf16x8*)&At[ar +  0][ao];
        bf16x8 a1 = *(const bf16x8*)&At[ar + 16][ao];
        bf16x8 a2 = *(const bf16x8*)&At[ar + 32][ao];
        bf16x8 a3 = *(const bf16x8*)&At[ar + 48][ao];
        const __hip_bfloat16* bb = Bp + ((size_t)((c * 4 + g) * 128) + bc) * 8;
        bf16x8 b0 = *(const bf16x8*)(bb);
        bf16x8 b1 = *(const bf16x8*)(bb + 128);
        acc[0][0] = __builtin_amdgcn_mfma_f32_16x16x32_bf16(a0, b0, acc[0][0], 0, 0, 0);
        acc[1][0] = __builtin_amdgcn_mfma_f32_16x16x32_bf16(a1, b0, acc[1][0], 0, 0, 0);
        acc[2][0] = __builtin_amdgcn_mfma_f32_16x16x32_bf16(a2, b0, acc[2][0], 0, 0, 0);
        acc[3][0] = __builtin_amdgcn_mfma_f32_16x16x32_bf16(a3, b0, acc[3][0], 0, 0, 0);
        acc[0][1] = __builtin_amdgcn_mfma_f32_16x16x32_bf16(a0, b1, acc[0][1], 0, 0, 0);
        acc[1][1] = __builtin_amdgcn_mfma_f32_16x16x32_bf16(a1, b1, acc[1][1], 0, 0, 0);
        acc[2][1] = __builtin_amdgcn_mfma_f32_16x16x32_bf16(a2, b1, acc[2][1], 0, 0, 0);
        acc[3][1] = __builtin_amdgcn_mfma_f32_16x16x32_bf16(a3, b1, acc[3][1], 0, 0, 0);
    }
}

__device__ __forceinline__ void zacc(f32x4 acc[4][2]) {
    #pragma unroll
    for (int r = 0; r < 4; ++r)
        #pragma unroll
        for (int c = 0; c < 2; ++c) acc[r][c] = (f32x4){0.f, 0.f, 0.f, 0.f};
}

// ======================= embed (fp32 VALU, small): h = hin @ embW + b ; writes f32 + bf16
__device__ __forceinline__ void gemm4x4(const float* __restrict__ Wg,
                                        const float* a0p, const float* a1p,
                                        const float* a2p, const float* a3p,
                                        int K, int o0, float acc[4][4]) {
    for (int k = 0; k < K; k += 4) {
        float4 a0 = *(const float4*)(a0p + k);
        float4 a1 = *(const float4*)(a1p + k);
        float4 a2 = *(const float4*)(a2p + k);
        float4 a3 = *(const float4*)(a3p + k);
        float4 w0 = *(const float4*)(Wg + (k + 0) * 128 + o0);
        float4 w1 = *(const float4*)(Wg + (k + 1) * 128 + o0);
        float4 w2 = *(const float4*)(Wg + (k + 2) * 128 + o0);
        float4 w3 = *(const float4*)(Wg + (k + 3) * 128 + o0);
        float av[4][4] = {{a0.x, a0.y, a0.z, a0.w}, {a1.x, a1.y, a1.z, a1.w},
                          {a2.x, a2.y, a2.z, a2.w}, {a3.x, a3.y, a3.z, a3.w}};
        float wv[4][4] = {{w0.x, w0.y, w0.z, w0.w}, {w1.x, w1.y, w1.z, w1.w},
                          {w2.x, w2.y, w2.z, w2.w}, {w3.x, w3.y, w3.z, w3.w}};
        #pragma unroll
        for (int i = 0; i < 4; ++i)
            #pragma unroll
            for (int kk = 0; kk < 4; ++kk)
                #pragma unroll
                for (int j = 0; j < 4; ++j)
                    acc[i][j] = fmaf(av[i][kk], wv[kk][j], acc[i][j]);
    }
}

__global__ __launch_bounds__(256) void embed_kernel(
    const float* __restrict__ hin, const float* __restrict__ W,
    const float* __restrict__ b, float* __restrict__ hbuf,
    __hip_bfloat16* __restrict__ h16, int N)
{
    __shared__ float in_tile[32][68];
    const int t = threadIdx.x;
    const int nb = blockIdx.x * 32;

    #pragma unroll
    for (int it = 0; it < 2; ++it) {
        int flat = t + 256 * it;
        int c = flat & 15, e = flat >> 4;
        int node = nb + e; if (node >= N) node = N - 1;
        *(float4*)(&in_tile[e][c * 4]) = *(const float4*)(hin + (size_t)node * 64 + c * 4);
    }
    __syncthreads();

    const int o0 = (t & 31) * 4;
    const int e0 = (t >> 5) * 4;
    float acc[4][4];
    #pragma unroll
    for (int i = 0; i < 4; ++i)
        #pragma unroll
        for (int j = 0; j < 4; ++j) acc[i][j] = 0.f;
    gemm4x4(W, &in_tile[e0][0], &in_tile[e0 + 1][0], &in_tile[e0 + 2][0], &in_tile[e0 + 3][0],
            64, o0, acc);
    float4 bv = *(const float4*)(b + o0);
    #pragma unroll
    for (int i = 0; i < 4; ++i) {
        int node = nb + e0 + i;
        if (node < N) {
            float v0 = acc[i][0] + bv.x, v1 = acc[i][1] + bv.y;
            float v2 = acc[i][2] + bv.z, v3 = acc[i][3] + bv.w;
            *(float4*)(&hbuf[(size_t)node * 128 + o0]) = make_float4(v0, v1, v2, v3);
            __hip_bfloat16* hp = h16 + (size_t)node * 128 + o0;
            hp[0] = __float2bfloat16(v0); hp[1] = __float2bfloat16(v1);
            hp[2] = __float2bfloat16(v2); hp[3] = __float2bfloat16(v3);
        }
    }
}

// ======================= per-layer edge kernel (MFMA)
__global__ __launch_bounds__(256) void edge_mfma_kernel(
    const __hip_bfloat16* __restrict__ h16, const float* __restrict__ posb,
    const int* __restrict__ ei,
    const __hip_bfloat16* __restrict__ W1p, const float* __restrict__ W1tail,
    const float* __restrict__ b1,
    const __hip_bfloat16* __restrict__ W2p, const float* __restrict__ b2,
    const __hip_bfloat16* __restrict__ cW1p, const float* __restrict__ cb1,
    const float* __restrict__ cW2, const float* __restrict__ cb2,
    float* __restrict__ agg, float* __restrict__ pdel,
    int E, int N)
{
    const int Etot = E + N;
    __shared__ __hip_bfloat16 a_t[64][264];   // [hi(0..127) | hj(128..255)]
    __shared__ __hip_bfloat16 m1s[64][136];
    __shared__ int   srcl[64], dstl[64];
    __shared__ float relt[3][64], distl[64], wsc[64], red[64][4];

    const int t = threadIdx.x;
    const int eb = blockIdx.x * 64;
    const int lane = t & 63, w = t >> 6, g = lane >> 4;

    if (t < 64) {
        int e = eb + t;
        int s = 0, d = 0;
        if (e < E)         { s = ei[e]; d = ei[E + e]; }
        else if (e < Etot) { s = d = e - E; }
        srcl[t] = s; dstl[t] = d;
        float rx = posb[3 * s + 0] - posb[3 * d + 0];
        float ry = posb[3 * s + 1] - posb[3 * d + 1];
        float rz = posb[3 * s + 2] - posb[3 * d + 2];
        float dist = sqrtf(rx * rx + ry * ry + rz * rz);
        relt[0][t] = rx; relt[1][t] = ry; relt[2][t] = rz;
        distl[t] = dist;
    }
    __syncthreads();

    // gather h16[dst] -> cols 0..127, h16[src] -> cols 128..255 (16B vector copies)
    #pragma unroll
    for (int it = 0; it < 8; ++it) {
        int flat = t + 256 * it;            // 0..2047
        int c = flat & 15, row = flat >> 4; // row 0..127
        int e = row >> 1, half = row & 1;
        int node = half ? srcl[e] : dstl[e];
        *(int4*)(&a_t[e][half * 128 + c * 8]) =
            *(const int4*)(h16 + (size_t)node * 128 + c * 8);
    }
    __syncthreads();

    const int colA = w * 32 + (lane & 15), colB = colA + 16;
    f32x4 acc[4][2];

    // ---- GEMM1: m1 = silu([hi|hj] @ W1[0:256] + dist*W1[256] + b1)
    zacc(acc);
    mfma_gemm<264>(a_t, 0, W1p, 8, w, lane, acc);
    {
        float b1a = b1[colA], b1b = b1[colB];
        float wta = W1tail[colA], wtb = W1tail[colB];
        #pragma unroll
        for (int r = 0; r < 4; ++r)
            #pragma unroll
            for (int q = 0; q < 4; ++q) {
                int row = r * 16 + g * 4 + q;
                float dv = distl[row];
                m1s[row][colA] = __float2bfloat16(silu_f(acc[r][0][q] + dv * wta + b1a));
                m1s[row][colB] = __float2bfloat16(silu_f(acc[r][1][q] + dv * wtb + b1b));
            }
    }
    __syncthreads();

    // ---- GEMM2: m2 = silu(m1 @ W2 + b2) -> atomic scatter to agg[dst]
    zacc(acc);
    mfma_gemm<136>(m1s, 0, W2p, 4, w, lane, acc);
    {
        float b2a = b2[colA], b2b = b2[colB];
        #pragma unroll
        for (int r = 0; r < 4; ++r)
            #pragma unroll
            for (int q = 0; q < 4; ++q) {
                int row = r * 16 + g * 4 + q;
                if (eb + row < Etot) {
                    float* ap = agg + (size_t)dstl[row] * 128;
                    atomicAdd(ap + colA, silu_f(acc[r][0][q] + b2a));
                    atomicAdd(ap + colB, silu_f(acc[r][1][q] + b2b));
                }
            }
    }
    __syncthreads();   // all m1s reads done before reuse

    // ---- coord: c1 = silu(hj @ cW1 + cb1)
    zacc(acc);
    mfma_gemm<264>(a_t, 128, cW1p, 4, w, lane, acc);
    {
        float cb1a = cb1[colA], cb1b = cb1[colB];
        #pragma unroll
        for (int r = 0; r < 4; ++r)
            #pragma unroll
            for (int q = 0; q < 4; ++q) {
                int row = r * 16 + g * 4 + q;
                m1s[row][colA] = __float2bfloat16(silu_f(acc[r][0][q] + cb1a));
                m1s[row][colB] = __float2bfloat16(silu_f(acc[r][1][q] + cb1b));
            }
    }
    __syncthreads();

    // ---- w[e] = c1 . cW2 + cb2 ; scale = w/(dist+eps) ; scatter pdel
    {
        int e = t >> 2, g4 = t & 3;
        float s = 0.f;
        #pragma unroll
        for (int m = 0; m < 32; ++m) {
            int k = g4 * 32 + m;
            s = fmaf(__bfloat162float(m1s[e][k]), cW2[k], s);
        }
        red[e][g4] = s;
    }
    __syncthreads();
    if (t < 64) {
        float s = red[t][0] + red[t][1] + red[t][2] + red[t][3] + cb2[0];
        wsc[t] = s / (distl[t] + EPSV);
    }
    __syncthreads();
    if (t < 192) {
        int e = t / 3, comp = t % 3;
        if (eb + e < Etot)
            atomicAdd(&pdel[(size_t)dstl[e] * 3 + comp], wsc[e] * relt[comp][e]);
    }
}

// ======================= per-layer node kernel (MFMA): h += MLP([h,agg]); pos += pdel
__global__ __launch_bounds__(256) void node_mfma_kernel(
    float* __restrict__ hbuf, __hip_bfloat16* __restrict__ h16,
    const float* __restrict__ agg,
    float* __restrict__ posb, const float* __restrict__ pdel,
    const __hip_bfloat16* __restrict__ W1p, const float* __restrict__ b1,
    const __hip_bfloat16* __restrict__ W2p, const float* __restrict__ b2,
    int N)
{
    __shared__ __hip_bfloat16 a_t[64][264];   // [h | agg]
    __shared__ __hip_bfloat16 us[64][136];
    const int t = threadIdx.x;
    const int nb = blockIdx.x * 64;
    const int lane = t & 63, w = t >> 6, g = lane >> 4;

    #pragma unroll
    for (int it = 0; it < 4; ++it) {
        int flat = t + 256 * it;            // 1024: h half
        int c = flat & 15, e = flat >> 4;
        int node = nb + e; if (node >= N) node = N - 1;
        *(int4*)(&a_t[e][c * 8]) = *(const int4*)(h16 + (size_t)node * 128 + c * 8);
    }
    #pragma unroll
    for (int it = 0; it < 8; ++it) {
        int flat = t + 256 * it;            // 2048: agg half f32 -> bf16
        int c = flat & 31, e = flat >> 5;
        int node = nb + e; if (node >= N) node = N - 1;
        float4 v = *(const float4*)(agg + (size_t)node * 128 + c * 4);
        __hip_bfloat16* p = &a_t[e][128 + c * 4];
        p[0] = __float2bfloat16(v.x); p[1] = __float2bfloat16(v.y);
        p[2] = __float2bfloat16(v.z); p[3] = __float2bfloat16(v.w);
    }
    __syncthreads();

    const int colA = w * 32 + (lane & 15), colB = colA + 16;
    f32x4 acc[4][2];

    zacc(acc);
    mfma_gemm<264>(a_t, 0, W1p, 8, w, lane, acc);
    {
        float b1a = b1[colA], b1b = b1[colB];
        #pragma unroll
        for (int r = 0; r < 4; ++r)
            #pragma unroll
            for (int q = 0; q < 4; ++q) {
                int row = r * 16 + g * 4 + q;
                us[row][colA] = __float2bfloat16(silu_f(acc[r][0][q] + b1a));
                us[row][colB] = __float2bfloat16(silu_f(acc[r][1][q] + b1b));
            }
    }
    __syncthreads();

    zacc(acc);
    mfma_gemm<136>(us, 0, W2p, 4, w, lane, acc);
    {
        float b2a = b2[colA], b2b = b2[colB];
        #pragma unroll
        for (int r = 0; r < 4; ++r)
            #pragma unroll
            for (int q = 0; q < 4; ++q) {
                int row = r * 16 + g * 4 + q;
                int node = nb + row;
                if (node < N) {
                    size_t off = (size_t)node * 128;
                    float va = hbuf[off + colA] + acc[r][0][q] + b2a;
                    float vb = hbuf[off + colB] + acc[r][1][q] + b2b;
                    hbuf[off + colA] = va; hbuf[off + colB] = vb;
                    h16[off + colA] = __float2bfloat16(va);
                    h16[off + colB] = __float2bfloat16(vb);
                }
            }
    }
    if (t < 192) {
        int e = t / 3, comp = t % 3;
        int node = nb + e;
        if (node < N) posb[3 * node + comp] += pdel[3 * node + comp];
    }
}

// ======================= output head (MFMA)
__global__ __launch_bounds__(256) void out_mfma_kernel(
    const __hip_bfloat16* __restrict__ h16,
    const __hip_bfloat16* __restrict__ W1p, const float* __restrict__ b1,
    const __hip_bfloat16* __restrict__ W2p, const float* __restrict__ b2,
    float* __restrict__ outp, int N)
{
    __shared__ __hip_bfloat16 a8[64][136];
    __shared__ __hip_bfloat16 us[64][136];
    const int t = threadIdx.x;
    const int nb = blockIdx.x * 64;
    const int lane = t & 63, w = t >> 6, g = lane >> 4;

    #pragma unroll
    for (int it = 0; it < 4; ++it) {
        int flat = t + 256 * it;
        int c = flat & 15, e = flat >> 4;
        int node = nb + e; if (node >= N) node = N - 1;
        *(int4*)(&a8[e][c * 8]) = *(const int4*)(h16 + (size_t)node * 128 + c * 8);
    }
    __syncthreads();

    const int colA = w * 32 + (lane & 15), colB = colA + 16;
    f32x4 acc[4][2];

    zacc(acc);
    mfma_gemm<136>(a8, 0, W1p, 4, w, lane, acc);
    {
        float b1a = b1[colA], b1b = b1[colB];
        #pragma unroll
        for (int r = 0; r < 4; ++r)
            #pragma unroll
            for (int q = 0; q < 4; ++q) {
                int row = r * 16 + g * 4 + q;
                us[row][colA] = __float2bfloat16(silu_f(acc[r][0][q] + b1a));
                us[row][colB] = __float2bfloat16(silu_f(acc[r][1][q] + b1b));
            }
    }
    __syncthreads();

    zacc(acc);
    mfma_gemm<136>(us, 0, W2p, 4, w, lane, acc);
    {
        float b2a = b2[colA], b2b = b2[colB];
        #pragma unroll
        for (int r = 0; r < 4; ++r)
            #pragma unroll
            for (int q = 0; q < 4; ++q) {
                int row = r * 16 + g * 4 + q;
                int node = nb + row;
                if (node < N) {
                    outp[(size_t)node * 128 + colA] = acc[r][0][q] + b2a;
                    outp[(size_t)node * 128 + colB] = acc[r][1][q] + b2b;
                }
            }
    }
}

// =======================
extern "C" void kernel_launch(void* const* d_in, const int* in_sizes, int n_in,
                              void* d_out, int out_size, void* d_ws, size_t ws_size,
                              hipStream_t stream)
{
    const float* hin  = (const float*)d_in[0];
    const float* pos  = (const float*)d_in[1];
    const int*   ei   = (const int*)d_in[2];
    const float* embW = (const float*)d_in[3];
    const float* embb = (const float*)d_in[4];
    const float* mW1  = (const float*)d_in[5];
    const float* mb1  = (const float*)d_in[6];
    const float* mW2  = (const float*)d_in[7];
    const float* mb2  = (const float*)d_in[8];
    const float* cW1  = (const float*)d_in[9];
    const float* cb1  = (const float*)d_in[10];
    const float* cW2  = (const float*)d_in[11];
    const float* cb2  = (const float*)d_in[12];
    const float* nW1  = (const float*)d_in[13];
    const float* nb1  = (const float*)d_in[14];
    const float* nW2  = (const float*)d_in[15];
    const float* nb2  = (const float*)d_in[16];
    const float* oW1  = (const float*)d_in[17];
    const float* ob1  = (const float*)d_in[18];
    const float* oW2  = (const float*)d_in[19];
    const float* ob2  = (const float*)d_in[20];

    const int N = in_sizes[0] / 64;
    const int E = in_sizes[2] / 2;
    const int Etot = E + N;

    float* hbuf = (float*)d_ws;                       // N*128 f32
    float* aggb = hbuf + (size_t)N * 128;             // N*128 f32
    float* posb = aggb + (size_t)N * 128;             // N*3
    float* pdel = posb + (size_t)N * 3;               // N*3
    __hip_bfloat16* h16 = (__hip_bfloat16*)(pdel + (size_t)N * 3);   // N*128 bf16
    __hip_bfloat16* packed = h16 + (size_t)N * 128;   // 120*4096 bf16
    float* outp = (float*)d_out;

    // ---- weight repack descriptors (order per layer: mW1,mW2,cW1,nW1,nW2; then oW1,oW2)
    PackArgs pa;
    int nm = 0; unsigned int poff = 0; int totalChunks = 0;
    auto addm = [&](const float* s, int kc) {
        pa.src[nm] = s; pa.doff[nm] = poff; pa.nchunk[nm] = kc;
        poff += (unsigned int)kc * 4096; totalChunks += kc; ++nm;
    };
    for (int l = 0; l < 4; ++l) {
        addm(mW1 + (size_t)l * 257 * 128, 8);
        addm(mW2 + (size_t)l * 128 * 128, 4);
        addm(cW1 + (size_t)l * 128 * 128, 4);
        addm(nW1 + (size_t)l * 256 * 128, 8);
        addm(nW2 + (size_t)l * 128 * 128, 4);
    }
    addm(oW1, 4);
    addm(oW2, 4);
    pa.nmat = nm;

    const unsigned int LSTRIDE = 28 * 4096;   // packed bf16 per layer

    hipMemcpyAsync(posb, pos, (size_t)N * 3 * sizeof(float),
                   hipMemcpyDeviceToDevice, stream);
    repack_kernel<<<totalChunks, 256, 0, stream>>>(pa, packed);

    const int nodeBlocks32 = (N + 31) / 32;
    const int nodeBlocks64 = (N + 63) / 64;
    const int edgeBlocks   = (Etot + 63) / 64;

    embed_kernel<<<nodeBlocks32, 256, 0, stream>>>(hin, embW, embb, hbuf, h16, N);

    for (int l = 0; l < 4; ++l) {
        hipMemsetAsync(aggb, 0, (size_t)N * 128 * sizeof(float), stream);
        hipMemsetAsync(pdel, 0, (size_t)N * 3 * sizeof(float), stream);
        const __hip_bfloat16* lp = packed + (size_t)l * LSTRIDE;
        edge_mfma_kernel<<<edgeBlocks, 256, 0, stream>>>(
            h16, posb, ei,
            lp,                 mW1 + (size_t)l * 257 * 128 + 256 * 128, mb1 + l * 128,
            lp + 8 * 4096,      mb2 + l * 128,
            lp + 12 * 4096,     cb1 + l * 128,
            cW2 + (size_t)l * 128, cb2 + l,
            aggb, pdel, E, N);
        node_mfma_kernel<<<nodeBlocks64, 256, 0, stream>>>(
            hbuf, h16, aggb, posb, pdel,
            lp + 16 * 4096,     nb1 + l * 128,
            lp + 24 * 4096,     nb2 + l * 128, N);
    }
    out_mfma_kernel<<<nodeBlocks64, 256, 0, stream>>>(
        h16, packed + (size_t)4 * LSTRIDE, ob1,
        packed + (size_t)4 * LSTRIDE + 4 * 4096, ob2, outp, N);

    hipMemcpyAsync(outp + (size_t)N * 128, posb, (size_t)N * 3 * sizeof(float),
                   hipMemcpyDeviceToDevice, stream);
}

// Round 3
// 1694.769 us; speedup vs baseline: 4.1327x; 1.3207x over previous
//
#include <hip/hip_runtime.h>
#include <hip/hip_bf16.h>

#define EPSV 1e-8f

typedef short bf16x8 __attribute__((ext_vector_type(8)));
typedef float f32x4  __attribute__((ext_vector_type(4)));

__device__ __forceinline__ float silu_f(float x) {
    return x / (1.0f + __expf(-x));
}
__device__ __forceinline__ float bf2f(short v) {
    return __uint_as_float(((unsigned int)(unsigned short)v) << 16);
}
__device__ __forceinline__ short f2bf(float f) {
    unsigned int u = __float_as_uint(f);
    unsigned int r = (u + 0x7fff + ((u >> 16) & 1)) >> 16;
    return (short)r;
}

// ======================= weight repack: f32 KxN(row-major, N=128) -> bf16 MFMA-B frags
#define MAXM 24
struct PackArgs {
    const float* src[MAXM];
    unsigned int doff[MAXM];
    int nchunk[MAXM];
    int nmat;
};

__global__ __launch_bounds__(256) void repack_kernel(PackArgs pa, __hip_bfloat16* base)
{
    int bid = blockIdx.x;
    int m = 0, c = bid;
    while (m < pa.nmat && c >= pa.nchunk[m]) { c -= pa.nchunk[m]; ++m; }
    const float* src = pa.src[m];
    __hip_bfloat16* dst = base + pa.doff[m] + (size_t)c * 4096;
    for (int o = threadIdx.x; o < 4096; o += 256) {
        int j = o & 7, n = (o >> 3) & 127, g = o >> 10;
        dst[o] = __float2bfloat16(src[(size_t)(c * 32 + g * 8 + j) * 128 + n]);
    }
}

// ======================= core MFMA tile GEMM (A in LDS, B packed global)
template<int LDA>
__device__ __forceinline__ void mfma_gemm(const __hip_bfloat16 (*At)[LDA], int acol0,
                                          const __hip_bfloat16* __restrict__ Bp,
                                          int kchunks, int w, int lane, f32x4 acc[4][2])
{
    const int ar = lane & 15, g = lane >> 4;
    const int bc = w * 32 + (lane & 15);
    for (int c = 0; c < kchunks; ++c) {
        const int ao = acol0 + c * 32 + g * 8;
        bf16x8 a0 = *(const bf16x8*)&At[ar +  0][ao];
        bf16x8 a1 = *(const bf16x8*)&At[ar + 16][ao];
        bf16x8 a2 = *(const bf16x8*)&At[ar + 32][ao];
        bf16x8 a3 = *(const bf16x8*)&At[ar + 48][ao];
        const __hip_bfloat16* bb = Bp + ((size_t)((c * 4 + g) * 128) + bc) * 8;
        bf16x8 b0 = *(const bf16x8*)(bb);
        bf16x8 b1 = *(const bf16x8*)(bb + 128);
        acc[0][0] = __builtin_amdgcn_mfma_f32_16x16x32_bf16(a0, b0, acc[0][0], 0, 0, 0);
        acc[1][0] = __builtin_amdgcn_mfma_f32_16x16x32_bf16(a1, b0, acc[1][0], 0, 0, 0);
        acc[2][0] = __builtin_amdgcn_mfma_f32_16x16x32_bf16(a2, b0, acc[2][0], 0, 0, 0);
        acc[3][0] = __builtin_amdgcn_mfma_f32_16x16x32_bf16(a3, b0, acc[3][0], 0, 0, 0);
        acc[0][1] = __builtin_amdgcn_mfma_f32_16x16x32_bf16(a0, b1, acc[0][1], 0, 0, 0);
        acc[1][1] = __builtin_amdgcn_mfma_f32_16x16x32_bf16(a1, b1, acc[1][1], 0, 0, 0);
        acc[2][1] = __builtin_amdgcn_mfma_f32_16x16x32_bf16(a2, b1, acc[2][1], 0, 0, 0);
        acc[3][1] = __builtin_amdgcn_mfma_f32_16x16x32_bf16(a3, b1, acc[3][1], 0, 0, 0);
    }
}

__device__ __forceinline__ void zacc(f32x4 acc[4][2]) {
    #pragma unroll
    for (int r = 0; r < 4; ++r)
        #pragma unroll
        for (int c = 0; c < 2; ++c) acc[r][c] = (f32x4){0.f, 0.f, 0.f, 0.f};
}

// ======================= embed (fp32): h = hin @ embW + b -> hbuf f32 + h16 bf16
__device__ __forceinline__ void gemm4x4(const float* __restrict__ Wg,
                                        const float* a0p, const float* a1p,
                                        const float* a2p, const float* a3p,
                                        int K, int o0, float acc[4][4]) {
    for (int k = 0; k < K; k += 4) {
        float4 a0 = *(const float4*)(a0p + k);
        float4 a1 = *(const float4*)(a1p + k);
        float4 a2 = *(const float4*)(a2p + k);
        float4 a3 = *(const float4*)(a3p + k);
        float4 w0 = *(const float4*)(Wg + (k + 0) * 128 + o0);
        float4 w1 = *(const float4*)(Wg + (k + 1) * 128 + o0);
        float4 w2 = *(const float4*)(Wg + (k + 2) * 128 + o0);
        float4 w3 = *(const float4*)(Wg + (k + 3) * 128 + o0);
        float av[4][4] = {{a0.x, a0.y, a0.z, a0.w}, {a1.x, a1.y, a1.z, a1.w},
                          {a2.x, a2.y, a2.z, a2.w}, {a3.x, a3.y, a3.z, a3.w}};
        float wv[4][4] = {{w0.x, w0.y, w0.z, w0.w}, {w1.x, w1.y, w1.z, w1.w},
                          {w2.x, w2.y, w2.z, w2.w}, {w3.x, w3.y, w3.z, w3.w}};
        #pragma unroll
        for (int i = 0; i < 4; ++i)
            #pragma unroll
            for (int kk = 0; kk < 4; ++kk)
                #pragma unroll
                for (int j = 0; j < 4; ++j)
                    acc[i][j] = fmaf(av[i][kk], wv[kk][j], acc[i][j]);
    }
}

__global__ __launch_bounds__(256) void embed_kernel(
    const float* __restrict__ hin, const float* __restrict__ W,
    const float* __restrict__ b, float* __restrict__ hbuf,
    __hip_bfloat16* __restrict__ h16, int N)
{
    __shared__ float in_tile[32][68];
    const int t = threadIdx.x;
    const int nb = blockIdx.x * 32;

    #pragma unroll
    for (int it = 0; it < 2; ++it) {
        int flat = t + 256 * it;
        int c = flat & 15, e = flat >> 4;
        int node = nb + e; if (node >= N) node = N - 1;
        *(float4*)(&in_tile[e][c * 4]) = *(const float4*)(hin + (size_t)node * 64 + c * 4);
    }
    __syncthreads();

    const int o0 = (t & 31) * 4;
    const int e0 = (t >> 5) * 4;
    float acc[4][4];
    #pragma unroll
    for (int i = 0; i < 4; ++i)
        #pragma unroll
        for (int j = 0; j < 4; ++j) acc[i][j] = 0.f;
    gemm4x4(W, &in_tile[e0][0], &in_tile[e0 + 1][0], &in_tile[e0 + 2][0], &in_tile[e0 + 3][0],
            64, o0, acc);
    float4 bv = *(const float4*)(b + o0);
    #pragma unroll
    for (int i = 0; i < 4; ++i) {
        int node = nb + e0 + i;
        if (node < N) {
            float v0 = acc[i][0] + bv.x, v1 = acc[i][1] + bv.y;
            float v2 = acc[i][2] + bv.z, v3 = acc[i][3] + bv.w;
            *(float4*)(&hbuf[(size_t)node * 128 + o0]) = make_float4(v0, v1, v2, v3);
            __hip_bfloat16* hp = h16 + (size_t)node * 128 + o0;
            hp[0] = __float2bfloat16(v0); hp[1] = __float2bfloat16(v1);
            hp[2] = __float2bfloat16(v2); hp[3] = __float2bfloat16(v3);
        }
    }
}

// ======================= per-layer node precompute: U = h@W1a, V = h@W1b,
// wnum[n] = silu(h@cW1 + cb1) . cW2 + cb2   (all per-node, dense, MFMA)
__global__ __launch_bounds__(256) void precompute_kernel(
    const __hip_bfloat16* __restrict__ h16,
    const __hip_bfloat16* __restrict__ W1p,   // 8 chunks: U=0..3, V=4..7
    const __hip_bfloat16* __restrict__ cW1p,  // 4 chunks
    const float* __restrict__ cb1, const float* __restrict__ cW2,
    const float* __restrict__ cb2,
    __hip_bfloat16* __restrict__ U16, __hip_bfloat16* __restrict__ V16,
    float* __restrict__ wnum, int N)
{
    __shared__ __hip_bfloat16 a8[64][136];
    __shared__ float redw[64][4];
    const int t = threadIdx.x;
    const int nb = blockIdx.x * 64;
    const int lane = t & 63, w = t >> 6, g = lane >> 4, l15 = lane & 15;

    #pragma unroll
    for (int it = 0; it < 4; ++it) {
        int flat = t + 256 * it;
        int c = flat & 15, e = flat >> 4;
        int node = nb + e; if (node >= N) node = N - 1;
        *(int4*)(&a8[e][c * 8]) = *(const int4*)(h16 + (size_t)node * 128 + c * 8);
    }
    __syncthreads();

    const int colA = w * 32 + l15, colB = colA + 16;
    f32x4 acc[4][2];

    // U
    zacc(acc);
    mfma_gemm<136>(a8, 0, W1p, 4, w, lane, acc);
    #pragma unroll
    for (int r = 0; r < 4; ++r)
        #pragma unroll
        for (int q = 0; q < 4; ++q) {
            int node = nb + r * 16 + g * 4 + q;
            if (node < N) {
                U16[(size_t)node * 128 + colA] = __float2bfloat16(acc[r][0][q]);
                U16[(size_t)node * 128 + colB] = __float2bfloat16(acc[r][1][q]);
            }
        }
    // V
    zacc(acc);
    mfma_gemm<136>(a8, 0, W1p + 4 * 4096, 4, w, lane, acc);
    #pragma unroll
    for (int r = 0; r < 4; ++r)
        #pragma unroll
        for (int q = 0; q < 4; ++q) {
            int node = nb + r * 16 + g * 4 + q;
            if (node < N) {
                V16[(size_t)node * 128 + colA] = __float2bfloat16(acc[r][1 - 1][q]);
                V16[(size_t)node * 128 + colB] = __float2bfloat16(acc[r][1][q]);
            }
        }
    // C1 dot cW2 (in-register, no store of C1)
    zacc(acc);
    mfma_gemm<136>(a8, 0, cW1p, 4, w, lane, acc);
    {
        float cb1A = cb1[colA], cb1B = cb1[colB];
        float wA = cW2[colA], wB = cW2[colB];
        #pragma unroll
        for (int r = 0; r < 4; ++r)
            #pragma unroll
            for (int q = 0; q < 4; ++q) {
                float p = silu_f(acc[r][0][q] + cb1A) * wA
                        + silu_f(acc[r][1][q] + cb1B) * wB;
                p += __shfl_xor(p, 1);
                p += __shfl_xor(p, 2);
                p += __shfl_xor(p, 4);
                p += __shfl_xor(p, 8);
                if (l15 == 0) redw[r * 16 + g * 4 + q][w] = p;
            }
    }
    __syncthreads();
    if (t < 64 && nb + t < N)
        wnum[nb + t] = redw[t][0] + redw[t][1] + redw[t][2] + redw[t][3] + cb2[0];
}

// ======================= per-layer edge kernel: m1 from gathered U/V, one GEMM,
// all atomics deferred past the last barrier
__global__ __launch_bounds__(256) void edge_kernel(
    const __hip_bfloat16* __restrict__ U16, const __hip_bfloat16* __restrict__ V16,
    const float* __restrict__ wnum, const float* __restrict__ posb,
    const int* __restrict__ ei,
    const float* __restrict__ W1tail, const float* __restrict__ b1,
    const __hip_bfloat16* __restrict__ W2p, const float* __restrict__ b2,
    float* __restrict__ agg, float* __restrict__ pdel,
    int E, int N)
{
    const int Etot = E + N;
    __shared__ __hip_bfloat16 m1s[64][136];
    __shared__ int   srcl[64], dstl[64];
    __shared__ float relt[3][64], distl[64], wscl[64];

    const int t = threadIdx.x;
    const int eb = blockIdx.x * 64;
    const int lane = t & 63, w = t >> 6, g = lane >> 4, l15 = lane & 15;

    if (t < 64) {
        int e = eb + t;
        int s = 0, d = 0;
        if (e < E)         { s = ei[e]; d = ei[E + e]; }
        else if (e < Etot) { s = d = e - E; }
        srcl[t] = s; dstl[t] = d;
        float rx = posb[3 * s + 0] - posb[3 * d + 0];
        float ry = posb[3 * s + 1] - posb[3 * d + 1];
        float rz = posb[3 * s + 2] - posb[3 * d + 2];
        float dist = sqrtf(rx * rx + ry * ry + rz * rz);
        relt[0][t] = rx; relt[1][t] = ry; relt[2][t] = rz;
        distl[t] = dist;
        wscl[t] = wnum[s] / (dist + EPSV);
    }
    __syncthreads();

    // fused gather + m1 = silu(U[dst] + V[src] + dist*wt + b1) -> m1s
    #pragma unroll
    for (int j = 0; j < 4; ++j) {
        int f = t + 256 * j;              // 1024 = 64 rows x 16 octets
        int c8 = f & 15, row = f >> 4;
        int s = srcl[row], d = dstl[row];
        bf16x8 uv = *(const bf16x8*)(U16 + (size_t)d * 128 + c8 * 8);
        bf16x8 vv = *(const bf16x8*)(V16 + (size_t)s * 128 + c8 * 8);
        float4 wt0 = *(const float4*)(W1tail + c8 * 8);
        float4 wt1 = *(const float4*)(W1tail + c8 * 8 + 4);
        float4 bb0 = *(const float4*)(b1 + c8 * 8);
        float4 bb1 = *(const float4*)(b1 + c8 * 8 + 4);
        float dv = distl[row];
        float wt[8] = {wt0.x, wt0.y, wt0.z, wt0.w, wt1.x, wt1.y, wt1.z, wt1.w};
        float bb[8] = {bb0.x, bb0.y, bb0.z, bb0.w, bb1.x, bb1.y, bb1.z, bb1.w};
        bf16x8 res;
        #pragma unroll
        for (int k = 0; k < 8; ++k) {
            float x = bf2f(uv[k]) + bf2f(vv[k]) + dv * wt[k] + bb[k];
            res[k] = f2bf(silu_f(x));
        }
        *(bf16x8*)(&m1s[row][c8 * 8]) = res;
    }
    __syncthreads();

    // GEMM2: m2 = silu(m1 @ W2 + b2)
    const int colA = w * 32 + l15, colB = colA + 16;
    f32x4 acc[4][2];
    zacc(acc);
    mfma_gemm<136>(m1s, 0, W2p, 4, w, lane, acc);

    // ---- deferred scatter phase (no barriers after this point) ----
    {
        float b2a = b2[colA], b2b = b2[colB];
        #pragma unroll
        for (int r = 0; r < 4; ++r)
            #pragma unroll
            for (int q = 0; q < 4; ++q) {
                int row = r * 16 + g * 4 + q;
                if (eb + row < Etot) {
                    float* ap = agg + (size_t)dstl[row] * 128;
                    atomicAdd(ap + colA, silu_f(acc[r][0][q] + b2a));
                    atomicAdd(ap + colB, silu_f(acc[r][1][q] + b2b));
                }
            }
    }
    if (t < 192) {
        int e = t / 3, comp = t % 3;
        if (eb + e < Etot)
            atomicAdd(&pdel[(size_t)dstl[e] * 3 + comp], wscl[e] * relt[comp][e]);
    }
}

// ======================= per-layer node kernel: h += MLP([h,agg]); pos += pdel
__global__ __launch_bounds__(256) void node_mfma_kernel(
    float* __restrict__ hbuf, __hip_bfloat16* __restrict__ h16,
    const float* __restrict__ agg,
    float* __restrict__ posb, const float* __restrict__ pdel,
    const __hip_bfloat16* __restrict__ W1p, const float* __restrict__ b1,
    const __hip_bfloat16* __restrict__ W2p, const float* __restrict__ b2,
    int N)
{
    __shared__ __hip_bfloat16 a_t[64][264];   // [h | agg]
    __shared__ __hip_bfloat16 us[64][136];
    const int t = threadIdx.x;
    const int nb = blockIdx.x * 64;
    const int lane = t & 63, w = t >> 6, g = lane >> 4;

    #pragma unroll
    for (int it = 0; it < 4; ++it) {
        int flat = t + 256 * it;            // h half
        int c = flat & 15, e = flat >> 4;
        int node = nb + e; if (node >= N) node = N - 1;
        *(int4*)(&a_t[e][c * 8]) = *(const int4*)(h16 + (size_t)node * 128 + c * 8);
    }
    #pragma unroll
    for (int it = 0; it < 8; ++it) {
        int flat = t + 256 * it;            // agg half f32 -> bf16
        int c = flat & 31, e = flat >> 5;
        int node = nb + e; if (node >= N) node = N - 1;
        float4 v = *(const float4*)(agg + (size_t)node * 128 + c * 4);
        __hip_bfloat16* p = &a_t[e][128 + c * 4];
        p[0] = __float2bfloat16(v.x); p[1] = __float2bfloat16(v.y);
        p[2] = __float2bfloat16(v.z); p[3] = __float2bfloat16(v.w);
    }
    __syncthreads();

    const int colA = w * 32 + (lane & 15), colB = colA + 16;
    f32x4 acc[4][2];

    zacc(acc);
    mfma_gemm<264>(a_t, 0, W1p, 8, w, lane, acc);
    {
        float b1a = b1[colA], b1b = b1[colB];
        #pragma unroll
        for (int r = 0; r < 4; ++r)
            #pragma unroll
            for (int q = 0; q < 4; ++q) {
                int row = r * 16 + g * 4 + q;
                us[row][colA] = __float2bfloat16(silu_f(acc[r][0][q] + b1a));
                us[row][colB] = __float2bfloat16(silu_f(acc[r][1][q] + b1b));
            }
    }
    __syncthreads();

    zacc(acc);
    mfma_gemm<136>(us, 0, W2p, 4, w, lane, acc);
    {
        float b2a = b2[colA], b2b = b2[colB];
        #pragma unroll
        for (int r = 0; r < 4; ++r)
            #pragma unroll
            for (int q = 0; q < 4; ++q) {
                int row = r * 16 + g * 4 + q;
                int node = nb + row;
                if (node < N) {
                    size_t off = (size_t)node * 128;
                    float va = hbuf[off + colA] + acc[r][0][q] + b2a;
                    float vb = hbuf[off + colB] + acc[r][1][q] + b2b;
                    hbuf[off + colA] = va; hbuf[off + colB] = vb;
                    h16[off + colA] = __float2bfloat16(va);
                    h16[off + colB] = __float2bfloat16(vb);
                }
            }
    }
    if (t < 192) {
        int e = t / 3, comp = t % 3;
        int node = nb + e;
        if (node < N) posb[3 * node + comp] += pdel[3 * node + comp];
    }
}

// ======================= output head (MFMA)
__global__ __launch_bounds__(256) void out_mfma_kernel(
    const __hip_bfloat16* __restrict__ h16,
    const __hip_bfloat16* __restrict__ W1p, const float* __restrict__ b1,
    const __hip_bfloat16* __restrict__ W2p, const float* __restrict__ b2,
    float* __restrict__ outp, int N)
{
    __shared__ __hip_bfloat16 a8[64][136];
    __shared__ __hip_bfloat16 us[64][136];
    const int t = threadIdx.x;
    const int nb = blockIdx.x * 64;
    const int lane = t & 63, w = t >> 6, g = lane >> 4;

    #pragma unroll
    for (int it = 0; it < 4; ++it) {
        int flat = t + 256 * it;
        int c = flat & 15, e = flat >> 4;
        int node = nb + e; if (node >= N) node = N - 1;
        *(int4*)(&a8[e][c * 8]) = *(const int4*)(h16 + (size_t)node * 128 + c * 8);
    }
    __syncthreads();

    const int colA = w * 32 + (lane & 15), colB = colA + 16;
    f32x4 acc[4][2];

    zacc(acc);
    mfma_gemm<136>(a8, 0, W1p, 4, w, lane, acc);
    {
        float b1a = b1[colA], b1b = b1[colB];
        #pragma unroll
        for (int r = 0; r < 4; ++r)
            #pragma unroll
            for (int q = 0; q < 4; ++q) {
                int row = r * 16 + g * 4 + q;
                us[row][colA] = __float2bfloat16(silu_f(acc[r][0][q] + b1a));
                us[row][colB] = __float2bfloat16(silu_f(acc[r][1][q] + b1b));
            }
    }
    __syncthreads();

    zacc(acc);
    mfma_gemm<136>(us, 0, W2p, 4, w, lane, acc);
    {
        float b2a = b2[colA], b2b = b2[colB];
        #pragma unroll
        for (int r = 0; r < 4; ++r)
            #pragma unroll
            for (int q = 0; q < 4; ++q) {
                int row = r * 16 + g * 4 + q;
                int node = nb + row;
                if (node < N) {
                    outp[(size_t)node * 128 + colA] = acc[r][0][q] + b2a;
                    outp[(size_t)node * 128 + colB] = acc[r][1][q] + b2b;
                }
            }
    }
}

// =======================
extern "C" void kernel_launch(void* const* d_in, const int* in_sizes, int n_in,
                              void* d_out, int out_size, void* d_ws, size_t ws_size,
                              hipStream_t stream)
{
    const float* hin  = (const float*)d_in[0];
    const float* pos  = (const float*)d_in[1];
    const int*   ei   = (const int*)d_in[2];
    const float* embW = (const float*)d_in[3];
    const float* embb = (const float*)d_in[4];
    const float* mW1  = (const float*)d_in[5];
    const float* mb1  = (const float*)d_in[6];
    const float* mW2  = (const float*)d_in[7];
    const float* mb2  = (const float*)d_in[8];
    const float* cW1  = (const float*)d_in[9];
    const float* cb1  = (const float*)d_in[10];
    const float* cW2  = (const float*)d_in[11];
    const float* cb2  = (const float*)d_in[12];
    const float* nW1  = (const float*)d_in[13];
    const float* nb1  = (const float*)d_in[14];
    const float* nW2  = (const float*)d_in[15];
    const float* nb2  = (const float*)d_in[16];
    const float* oW1  = (const float*)d_in[17];
    const float* ob1  = (const float*)d_in[18];
    const float* oW2  = (const float*)d_in[19];
    const float* ob2  = (const float*)d_in[20];

    const int N = in_sizes[0] / 64;
    const int E = in_sizes[2] / 2;
    const int Etot = E + N;

    float* hbuf = (float*)d_ws;                                  // N*128 f32
    float* aggb = hbuf + (size_t)N * 128;                        // N*128 f32
    float* posb = aggb + (size_t)N * 128;                        // N*3
    float* pdel = posb + (size_t)N * 3;                          // N*3
    float* wnum = pdel + (size_t)N * 3;                          // N f32
    __hip_bfloat16* h16 = (__hip_bfloat16*)(wnum + N);           // N*128 bf16
    __hip_bfloat16* U16 = h16 + (size_t)N * 128;                 // N*128 bf16
    __hip_bfloat16* V16 = U16 + (size_t)N * 128;                 // N*128 bf16
    __hip_bfloat16* packed = V16 + (size_t)N * 128;              // 120*4096 bf16
    float* outp = (float*)d_out;

    // ---- weight repack (order per layer: mW1(8), mW2(4), cW1(4), nW1(8), nW2(4); then oW1, oW2)
    PackArgs pa;
    int nm = 0; unsigned int poff = 0; int totalChunks = 0;
    auto addm = [&](const float* s, int kc) {
        pa.src[nm] = s; pa.doff[nm] = poff; pa.nchunk[nm] = kc;
        poff += (unsigned int)kc * 4096; totalChunks += kc; ++nm;
    };
    for (int l = 0; l < 4; ++l) {
        addm(mW1 + (size_t)l * 257 * 128, 8);
        addm(mW2 + (size_t)l * 128 * 128, 4);
        addm(cW1 + (size_t)l * 128 * 128, 4);
        addm(nW1 + (size_t)l * 256 * 128, 8);
        addm(nW2 + (size_t)l * 128 * 128, 4);
    }
    addm(oW1, 4);
    addm(oW2, 4);
    pa.nmat = nm;

    const unsigned int LSTRIDE = 28 * 4096;

    hipMemcpyAsync(posb, pos, (size_t)N * 3 * sizeof(float),
                   hipMemcpyDeviceToDevice, stream);
    repack_kernel<<<totalChunks, 256, 0, stream>>>(pa, packed);

    const int nodeBlocks32 = (N + 31) / 32;
    const int nodeBlocks64 = (N + 63) / 64;
    const int edgeBlocks   = (Etot + 63) / 64;

    embed_kernel<<<nodeBlocks32, 256, 0, stream>>>(hin, embW, embb, hbuf, h16, N);

    // precompute for layer 0
    precompute_kernel<<<nodeBlocks64, 256, 0, stream>>>(
        h16, packed, packed + 12 * 4096,
        cb1, cW2, cb2, U16, V16, wnum, N);

    for (int l = 0; l < 4; ++l) {
        hipMemsetAsync(aggb, 0, (size_t)N * 128 * sizeof(float), stream);
        hipMemsetAsync(pdel, 0, (size_t)N * 3 * sizeof(float), stream);
        const __hip_bfloat16* lp = packed + (size_t)l * LSTRIDE;
        edge_kernel<<<edgeBlocks, 256, 0, stream>>>(
            U16, V16, wnum, posb, ei,
            mW1 + (size_t)l * 257 * 128 + 256 * 128, mb1 + l * 128,
            lp + 8 * 4096, mb2 + l * 128,
            aggb, pdel, E, N);
        node_mfma_kernel<<<nodeBlocks64, 256, 0, stream>>>(
            hbuf, h16, aggb, posb, pdel,
            lp + 16 * 4096, nb1 + l * 128,
            lp + 24 * 4096, nb2 + l * 128, N);
        if (l < 3) {
            const __hip_bfloat16* lpn = packed + (size_t)(l + 1) * LSTRIDE;
            precompute_kernel<<<nodeBlocks64, 256, 0, stream>>>(
                h16, lpn, lpn + 12 * 4096,
                cb1 + (l + 1) * 128, cW2 + (size_t)(l + 1) * 128, cb2 + (l + 1),
                U16, V16, wnum, N);
        }
    }
    out_mfma_kernel<<<nodeBlocks64, 256, 0, stream>>>(
        h16, packed + (size_t)4 * LSTRIDE, ob1,
        packed + (size_t)4 * LSTRIDE + 4 * 4096, ob2, outp, N);

    hipMemcpyAsync(outp + (size_t)N * 128, posb, (size_t)N * 3 * sizeof(float),
                   hipMemcpyDeviceToDevice, stream);
}

// Round 4
// 1103.188 us; speedup vs baseline: 6.3488x; 1.5362x over previous
//
#include <hip/hip_runtime.h>
#include <hip/hip_bf16.h>

#define EPSV 1e-8f

typedef short bf16x8 __attribute__((ext_vector_type(8)));
typedef float f32x4  __attribute__((ext_vector_type(4)));

__device__ __forceinline__ float silu_f(float x) {
    return x / (1.0f + __expf(-x));
}
__device__ __forceinline__ float bf2f(short v) {
    return __uint_as_float(((unsigned int)(unsigned short)v) << 16);
}
__device__ __forceinline__ short f2bf(float f) {
    unsigned int u = __float_as_uint(f);
    unsigned int r = (u + 0x7fff + ((u >> 16) & 1)) >> 16;
    return (short)r;
}

// ======================= weight repack: f32 KxN(row-major, N=128) -> bf16 MFMA-B frags
#define MAXM 24
struct PackArgs {
    const float* src[MAXM];
    unsigned int doff[MAXM];
    int nchunk[MAXM];
    int nmat;
};

__global__ __launch_bounds__(256) void repack_kernel(PackArgs pa, __hip_bfloat16* base)
{
    int bid = blockIdx.x;
    int m = 0, c = bid;
    while (m < pa.nmat && c >= pa.nchunk[m]) { c -= pa.nchunk[m]; ++m; }
    const float* src = pa.src[m];
    __hip_bfloat16* dst = base + pa.doff[m] + (size_t)c * 4096;
    for (int o = threadIdx.x; o < 4096; o += 256) {
        int j = o & 7, n = (o >> 3) & 127, g = o >> 10;
        dst[o] = __float2bfloat16(src[(size_t)(c * 32 + g * 8 + j) * 128 + n]);
    }
}

// ======================= edge dst-sort: histogram -> scan -> scatter
__global__ __launch_bounds__(256) void hist_kernel(
    const int* __restrict__ ei, int* __restrict__ cnt, int E, int N)
{
    int e = blockIdx.x * 256 + threadIdx.x;
    int Etot = E + N;
    if (e < Etot) {
        int d = (e < E) ? ei[E + e] : (e - E);
        atomicAdd(&cnt[d], 1);
    }
}

// block-scan: 4096 items/block (256 thr x 16); off = exclusive-within-block, part[b]=total
__global__ __launch_bounds__(256) void scan_block_kernel(
    const int* __restrict__ cnt, int* __restrict__ off, int* __restrict__ part, int n)
{
    __shared__ int sdata[256];
    const int tid = threadIdx.x;
    const int base = blockIdx.x * 4096 + tid * 16;
    int loc[16]; int s = 0;
    #pragma unroll
    for (int i = 0; i < 16; ++i) {
        int idx = base + i;
        int v = (idx < n) ? cnt[idx] : 0;
        loc[i] = s; s += v;
    }
    sdata[tid] = s;
    __syncthreads();
    for (int st = 1; st < 256; st <<= 1) {
        int v = (tid >= st) ? sdata[tid - st] : 0;
        __syncthreads();
        sdata[tid] += v;
        __syncthreads();
    }
    int texc = (tid > 0) ? sdata[tid - 1] : 0;
    #pragma unroll
    for (int i = 0; i < 16; ++i) {
        int idx = base + i;
        if (idx < n) off[idx] = texc + loc[i];
    }
    if (tid == 255) part[blockIdx.x] = sdata[255];
}

__global__ void scan_part_kernel(int* part, int np)
{
    if (threadIdx.x == 0 && blockIdx.x == 0) {
        int run = 0;
        for (int i = 0; i < np; ++i) { int v = part[i]; part[i] = run; run += v; }
    }
}

__global__ __launch_bounds__(256) void scan_add_kernel(
    int* __restrict__ off, const int* __restrict__ part, int n)
{
    int idx = blockIdx.x * 4096 + threadIdx.x * 16;
    int p = part[blockIdx.x];
    #pragma unroll
    for (int i = 0; i < 16; ++i)
        if (idx + i < n) off[idx + i] += p;
}

__global__ __launch_bounds__(256) void scatter_kernel(
    const int* __restrict__ ei, int* __restrict__ off,
    int* __restrict__ esrc, int* __restrict__ edst, int E, int N)
{
    int e = blockIdx.x * 256 + threadIdx.x;
    int Etot = E + N;
    if (e < Etot) {
        int s, d;
        if (e < E) { s = ei[e]; d = ei[E + e]; }
        else       { s = d = e - E; }
        int p = atomicAdd(&off[d], 1);
        esrc[p] = s; edst[p] = d;
    }
}

// ======================= core MFMA tile GEMM (A in LDS, B packed global)
template<int LDA>
__device__ __forceinline__ void mfma_gemm(const __hip_bfloat16 (*At)[LDA], int acol0,
                                          const __hip_bfloat16* __restrict__ Bp,
                                          int kchunks, int w, int lane, f32x4 acc[4][2])
{
    const int ar = lane & 15, g = lane >> 4;
    const int bc = w * 32 + (lane & 15);
    for (int c = 0; c < kchunks; ++c) {
        const int ao = acol0 + c * 32 + g * 8;
        bf16x8 a0 = *(const bf16x8*)&At[ar +  0][ao];
        bf16x8 a1 = *(const bf16x8*)&At[ar + 16][ao];
        bf16x8 a2 = *(const bf16x8*)&At[ar + 32][ao];
        bf16x8 a3 = *(const bf16x8*)&At[ar + 48][ao];
        const __hip_bfloat16* bb = Bp + ((size_t)((c * 4 + g) * 128) + bc) * 8;
        bf16x8 b0 = *(const bf16x8*)(bb);
        bf16x8 b1 = *(const bf16x8*)(bb + 128);
        acc[0][0] = __builtin_amdgcn_mfma_f32_16x16x32_bf16(a0, b0, acc[0][0], 0, 0, 0);
        acc[1][0] = __builtin_amdgcn_mfma_f32_16x16x32_bf16(a1, b0, acc[1][0], 0, 0, 0);
        acc[2][0] = __builtin_amdgcn_mfma_f32_16x16x32_bf16(a2, b0, acc[2][0], 0, 0, 0);
        acc[3][0] = __builtin_amdgcn_mfma_f32_16x16x32_bf16(a3, b0, acc[3][0], 0, 0, 0);
        acc[0][1] = __builtin_amdgcn_mfma_f32_16x16x32_bf16(a0, b1, acc[0][1], 0, 0, 0);
        acc[1][1] = __builtin_amdgcn_mfma_f32_16x16x32_bf16(a1, b1, acc[1][1], 0, 0, 0);
        acc[2][1] = __builtin_amdgcn_mfma_f32_16x16x32_bf16(a2, b1, acc[2][1], 0, 0, 0);
        acc[3][1] = __builtin_amdgcn_mfma_f32_16x16x32_bf16(a3, b1, acc[3][1], 0, 0, 0);
    }
}

__device__ __forceinline__ void zacc(f32x4 acc[4][2]) {
    #pragma unroll
    for (int r = 0; r < 4; ++r)
        #pragma unroll
        for (int c = 0; c < 2; ++c) acc[r][c] = (f32x4){0.f, 0.f, 0.f, 0.f};
}

// ======================= embed (fp32): h = hin @ embW + b -> hbuf f32 + h16 bf16
__device__ __forceinline__ void gemm4x4(const float* __restrict__ Wg,
                                        const float* a0p, const float* a1p,
                                        const float* a2p, const float* a3p,
                                        int K, int o0, float acc[4][4]) {
    for (int k = 0; k < K; k += 4) {
        float4 a0 = *(const float4*)(a0p + k);
        float4 a1 = *(const float4*)(a1p + k);
        float4 a2 = *(const float4*)(a2p + k);
        float4 a3 = *(const float4*)(a3p + k);
        float4 w0 = *(const float4*)(Wg + (k + 0) * 128 + o0);
        float4 w1 = *(const float4*)(Wg + (k + 1) * 128 + o0);
        float4 w2 = *(const float4*)(Wg + (k + 2) * 128 + o0);
        float4 w3 = *(const float4*)(Wg + (k + 3) * 128 + o0);
        float av[4][4] = {{a0.x, a0.y, a0.z, a0.w}, {a1.x, a1.y, a1.z, a1.w},
                          {a2.x, a2.y, a2.z, a2.w}, {a3.x, a3.y, a3.z, a3.w}};
        float wv[4][4] = {{w0.x, w0.y, w0.z, w0.w}, {w1.x, w1.y, w1.z, w1.w},
                          {w2.x, w2.y, w2.z, w2.w}, {w3.x, w3.y, w3.z, w3.w}};
        #pragma unroll
        for (int i = 0; i < 4; ++i)
            #pragma unroll
            for (int kk = 0; kk < 4; ++kk)
                #pragma unroll
                for (int j = 0; j < 4; ++j)
                    acc[i][j] = fmaf(av[i][kk], wv[kk][j], acc[i][j]);
    }
}

__global__ __launch_bounds__(256) void embed_kernel(
    const float* __restrict__ hin, const float* __restrict__ W,
    const float* __restrict__ b, float* __restrict__ hbuf,
    __hip_bfloat16* __restrict__ h16, int N)
{
    __shared__ float in_tile[32][68];
    const int t = threadIdx.x;
    const int nb = blockIdx.x * 32;

    #pragma unroll
    for (int it = 0; it < 2; ++it) {
        int flat = t + 256 * it;
        int c = flat & 15, e = flat >> 4;
        int node = nb + e; if (node >= N) node = N - 1;
        *(float4*)(&in_tile[e][c * 4]) = *(const float4*)(hin + (size_t)node * 64 + c * 4);
    }
    __syncthreads();

    const int o0 = (t & 31) * 4;
    const int e0 = (t >> 5) * 4;
    float acc[4][4];
    #pragma unroll
    for (int i = 0; i < 4; ++i)
        #pragma unroll
        for (int j = 0; j < 4; ++j) acc[i][j] = 0.f;
    gemm4x4(W, &in_tile[e0][0], &in_tile[e0 + 1][0], &in_tile[e0 + 2][0], &in_tile[e0 + 3][0],
            64, o0, acc);
    float4 bv = *(const float4*)(b + o0);
    #pragma unroll
    for (int i = 0; i < 4; ++i) {
        int node = nb + e0 + i;
        if (node < N) {
            float v0 = acc[i][0] + bv.x, v1 = acc[i][1] + bv.y;
            float v2 = acc[i][2] + bv.z, v3 = acc[i][3] + bv.w;
            *(float4*)(&hbuf[(size_t)node * 128 + o0]) = make_float4(v0, v1, v2, v3);
            __hip_bfloat16* hp = h16 + (size_t)node * 128 + o0;
            hp[0] = __float2bfloat16(v0); hp[1] = __float2bfloat16(v1);
            hp[2] = __float2bfloat16(v2); hp[3] = __float2bfloat16(v3);
        }
    }
}

// ======================= per-layer node precompute: U = h@W1a, V = h@W1b,
// wnum[n] = silu(h@cW1 + cb1) . cW2 + cb2
__global__ __launch_bounds__(256) void precompute_kernel(
    const __hip_bfloat16* __restrict__ h16,
    const __hip_bfloat16* __restrict__ W1p,
    const __hip_bfloat16* __restrict__ cW1p,
    const float* __restrict__ cb1, const float* __restrict__ cW2,
    const float* __restrict__ cb2,
    __hip_bfloat16* __restrict__ U16, __hip_bfloat16* __restrict__ V16,
    float* __restrict__ wnum, int N)
{
    __shared__ __hip_bfloat16 a8[64][136];
    __shared__ float redw[64][4];
    const int t = threadIdx.x;
    const int nb = blockIdx.x * 64;
    const int lane = t & 63, w = t >> 6, g = lane >> 4, l15 = lane & 15;

    #pragma unroll
    for (int it = 0; it < 4; ++it) {
        int flat = t + 256 * it;
        int c = flat & 15, e = flat >> 4;
        int node = nb + e; if (node >= N) node = N - 1;
        *(int4*)(&a8[e][c * 8]) = *(const int4*)(h16 + (size_t)node * 128 + c * 8);
    }
    __syncthreads();

    const int colA = w * 32 + l15, colB = colA + 16;
    f32x4 acc[4][2];

    // U
    zacc(acc);
    mfma_gemm<136>(a8, 0, W1p, 4, w, lane, acc);
    #pragma unroll
    for (int r = 0; r < 4; ++r)
        #pragma unroll
        for (int q = 0; q < 4; ++q) {
            int node = nb + r * 16 + g * 4 + q;
            if (node < N) {
                U16[(size_t)node * 128 + colA] = __float2bfloat16(acc[r][0][q]);
                U16[(size_t)node * 128 + colB] = __float2bfloat16(acc[r][1][q]);
            }
        }
    // V
    zacc(acc);
    mfma_gemm<136>(a8, 0, W1p + 4 * 4096, 4, w, lane, acc);
    #pragma unroll
    for (int r = 0; r < 4; ++r)
        #pragma unroll
        for (int q = 0; q < 4; ++q) {
            int node = nb + r * 16 + g * 4 + q;
            if (node < N) {
                V16[(size_t)node * 128 + colA] = __float2bfloat16(acc[r][0][q]);
                V16[(size_t)node * 128 + colB] = __float2bfloat16(acc[r][1][q]);
            }
        }
    // silu(h@cW1+cb1) . cW2
    zacc(acc);
    mfma_gemm<136>(a8, 0, cW1p, 4, w, lane, acc);
    {
        float cb1A = cb1[colA], cb1B = cb1[colB];
        float wA = cW2[colA], wB = cW2[colB];
        #pragma unroll
        for (int r = 0; r < 4; ++r)
            #pragma unroll
            for (int q = 0; q < 4; ++q) {
                float p = silu_f(acc[r][0][q] + cb1A) * wA
                        + silu_f(acc[r][1][q] + cb1B) * wB;
                p += __shfl_xor(p, 1);
                p += __shfl_xor(p, 2);
                p += __shfl_xor(p, 4);
                p += __shfl_xor(p, 8);
                if (l15 == 0) redw[r * 16 + g * 4 + q][w] = p;
            }
    }
    __syncthreads();
    if (t < 64 && nb + t < N)
        wnum[nb + t] = redw[t][0] + redw[t][1] + redw[t][2] + redw[t][3] + cb2[0];
}

// ======================= per-layer edge kernel (dst-sorted edges, segmented reduce)
__global__ __launch_bounds__(256) void edge_kernel(
    const __hip_bfloat16* __restrict__ U16, const __hip_bfloat16* __restrict__ V16,
    const float* __restrict__ wnum, const float* __restrict__ posb,
    const int* __restrict__ esrc, const int* __restrict__ edst,
    const float* __restrict__ W1tail, const float* __restrict__ b1,
    const __hip_bfloat16* __restrict__ W2p, const float* __restrict__ b2,
    float* __restrict__ agg, float* __restrict__ pdel, int Etot)
{
    __shared__ __hip_bfloat16 m1s[64][136];    // reused for m2 after GEMM2
    __shared__ int   srcl[64], dstl[64];
    __shared__ float relt[3][64], distl[64], wscl[64];

    const int t = threadIdx.x;
    const int eb = blockIdx.x * 64;
    const int lane = t & 63, w = t >> 6, g = lane >> 4, l15 = lane & 15;

    if (t < 64) {
        int e = eb + t;
        int s = 0, d = -1;
        if (e < Etot) { s = esrc[e]; d = edst[e]; }
        srcl[t] = s; dstl[t] = d;
        int dd = (d < 0) ? 0 : d;
        float rx = posb[3 * s + 0] - posb[3 * dd + 0];
        float ry = posb[3 * s + 1] - posb[3 * dd + 1];
        float rz = posb[3 * s + 2] - posb[3 * dd + 2];
        float dist = sqrtf(rx * rx + ry * ry + rz * rz);
        relt[0][t] = rx; relt[1][t] = ry; relt[2][t] = rz;
        distl[t] = dist;
        wscl[t] = wnum[s] / (dist + EPSV);
    }
    __syncthreads();

    // m1 = silu(U[dst] + V[src] + dist*wt + b1)
    #pragma unroll
    for (int j = 0; j < 4; ++j) {
        int f = t + 256 * j;              // 1024 = 64 rows x 16 octets
        int c8 = f & 15, row = f >> 4;
        bf16x8 res;
        if (dstl[row] >= 0) {
            int s = srcl[row], d = dstl[row];
            bf16x8 uv = *(const bf16x8*)(U16 + (size_t)d * 128 + c8 * 8);
            bf16x8 vv = *(const bf16x8*)(V16 + (size_t)s * 128 + c8 * 8);
            float4 wt0 = *(const float4*)(W1tail + c8 * 8);
            float4 wt1 = *(const float4*)(W1tail + c8 * 8 + 4);
            float4 bb0 = *(const float4*)(b1 + c8 * 8);
            float4 bb1 = *(const float4*)(b1 + c8 * 8 + 4);
            float dv = distl[row];
            float wt[8] = {wt0.x, wt0.y, wt0.z, wt0.w, wt1.x, wt1.y, wt1.z, wt1.w};
            float bb[8] = {bb0.x, bb0.y, bb0.z, bb0.w, bb1.x, bb1.y, bb1.z, bb1.w};
            #pragma unroll
            for (int k = 0; k < 8; ++k) {
                float x = bf2f(uv[k]) + bf2f(vv[k]) + dv * wt[k] + bb[k];
                res[k] = f2bf(silu_f(x));
            }
        } else {
            #pragma unroll
            for (int k = 0; k < 8; ++k) res[k] = 0;
        }
        *(bf16x8*)(&m1s[row][c8 * 8]) = res;
    }
    __syncthreads();

    // GEMM2: m2 = m1 @ W2
    const int colA = w * 32 + l15, colB = colA + 16;
    f32x4 acc[4][2];
    zacc(acc);
    mfma_gemm<136>(m1s, 0, W2p, 4, w, lane, acc);
    __syncthreads();   // all m1s reads done; safe to overwrite with m2

    // write silu(m2 + b2) back into the same LDS (bf16)
    {
        float b2a = b2[colA], b2b = b2[colB];
        #pragma unroll
        for (int r = 0; r < 4; ++r)
            #pragma unroll
            for (int q = 0; q < 4; ++q) {
                int row = r * 16 + g * 4 + q;
                m1s[row][colA] = __float2bfloat16(silu_f(acc[r][0][q] + b2a));
                m1s[row][colB] = __float2bfloat16(silu_f(acc[r][1][q] + b2b));
            }
    }
    __syncthreads();

    // segmented reduction by dst (rows sorted): one atomic per (segment, col)
    {
        int col = t & 127, half = t >> 7;
        int r0 = half * 32;
        float a = 0.f;
        int cur = dstl[r0];
        #pragma unroll 4
        for (int r = r0; r < r0 + 32; ++r) {
            int d = dstl[r];
            if (d != cur) {
                if (cur >= 0) atomicAdd(&agg[(size_t)cur * 128 + col], a);
                a = 0.f; cur = d;
            }
            if (d >= 0) a += bf2f(*(const short*)&m1s[r][col]);
        }
        if (cur >= 0) atomicAdd(&agg[(size_t)cur * 128 + col], a);
    }

    // pdel scatter (per-edge, small)
    if (t < 192) {
        int e = t / 3, comp = t % 3;
        if (dstl[e] >= 0)
            atomicAdd(&pdel[(size_t)dstl[e] * 3 + comp], wscl[e] * relt[comp][e]);
    }
}

// ======================= per-layer node kernel: h += MLP([h,agg]); pos += pdel
__global__ __launch_bounds__(256) void node_mfma_kernel(
    float* __restrict__ hbuf, __hip_bfloat16* __restrict__ h16,
    const float* __restrict__ agg,
    float* __restrict__ posb, const float* __restrict__ pdel,
    const __hip_bfloat16* __restrict__ W1p, const float* __restrict__ b1,
    const __hip_bfloat16* __restrict__ W2p, const float* __restrict__ b2,
    int N)
{
    __shared__ __hip_bfloat16 a_t[64][264];   // [h | agg]
    __shared__ __hip_bfloat16 us[64][136];
    const int t = threadIdx.x;
    const int nb = blockIdx.x * 64;
    const int lane = t & 63, w = t >> 6, g = lane >> 4;

    #pragma unroll
    for (int it = 0; it < 4; ++it) {
        int flat = t + 256 * it;
        int c = flat & 15, e = flat >> 4;
        int node = nb + e; if (node >= N) node = N - 1;
        *(int4*)(&a_t[e][c * 8]) = *(const int4*)(h16 + (size_t)node * 128 + c * 8);
    }
    #pragma unroll
    for (int it = 0; it < 8; ++it) {
        int flat = t + 256 * it;
        int c = flat & 31, e = flat >> 5;
        int node = nb + e; if (node >= N) node = N - 1;
        float4 v = *(const float4*)(agg + (size_t)node * 128 + c * 4);
        __hip_bfloat16* p = &a_t[e][128 + c * 4];
        p[0] = __float2bfloat16(v.x); p[1] = __float2bfloat16(v.y);
        p[2] = __float2bfloat16(v.z); p[3] = __float2bfloat16(v.w);
    }
    __syncthreads();

    const int colA = w * 32 + (lane & 15), colB = colA + 16;
    f32x4 acc[4][2];

    zacc(acc);
    mfma_gemm<264>(a_t, 0, W1p, 8, w, lane, acc);
    {
        float b1a = b1[colA], b1b = b1[colB];
        #pragma unroll
        for (int r = 0; r < 4; ++r)
            #pragma unroll
            for (int q = 0; q < 4; ++q) {
                int row = r * 16 + g * 4 + q;
                us[row][colA] = __float2bfloat16(silu_f(acc[r][0][q] + b1a));
                us[row][colB] = __float2bfloat16(silu_f(acc[r][1][q] + b1b));
            }
    }
    __syncthreads();

    zacc(acc);
    mfma_gemm<136>(us, 0, W2p, 4, w, lane, acc);
    {
        float b2a = b2[colA], b2b = b2[colB];
        #pragma unroll
        for (int r = 0; r < 4; ++r)
            #pragma unroll
            for (int q = 0; q < 4; ++q) {
                int row = r * 16 + g * 4 + q;
                int node = nb + row;
                if (node < N) {
                    size_t off = (size_t)node * 128;
                    float va = hbuf[off + colA] + acc[r][0][q] + b2a;
                    float vb = hbuf[off + colB] + acc[r][1][q] + b2b;
                    hbuf[off + colA] = va; hbuf[off + colB] = vb;
                    h16[off + colA] = __float2bfloat16(va);
                    h16[off + colB] = __float2bfloat16(vb);
                }
            }
    }
    if (t < 192) {
        int e = t / 3, comp = t % 3;
        int node = nb + e;
        if (node < N) posb[3 * node + comp] += pdel[3 * node + comp];
    }
}

// ======================= output head (MFMA)
__global__ __launch_bounds__(256) void out_mfma_kernel(
    const __hip_bfloat16* __restrict__ h16,
    const __hip_bfloat16* __restrict__ W1p, const float* __restrict__ b1,
    const __hip_bfloat16* __restrict__ W2p, const float* __restrict__ b2,
    float* __restrict__ outp, int N)
{
    __shared__ __hip_bfloat16 a8[64][136];
    __shared__ __hip_bfloat16 us[64][136];
    const int t = threadIdx.x;
    const int nb = blockIdx.x * 64;
    const int lane = t & 63, w = t >> 6, g = lane >> 4;

    #pragma unroll
    for (int it = 0; it < 4; ++it) {
        int flat = t + 256 * it;
        int c = flat & 15, e = flat >> 4;
        int node = nb + e; if (node >= N) node = N - 1;
        *(int4*)(&a8[e][c * 8]) = *(const int4*)(h16 + (size_t)node * 128 + c * 8);
    }
    __syncthreads();

    const int colA = w * 32 + (lane & 15), colB = colA + 16;
    f32x4 acc[4][2];

    zacc(acc);
    mfma_gemm<136>(a8, 0, W1p, 4, w, lane, acc);
    {
        float b1a = b1[colA], b1b = b1[colB];
        #pragma unroll
        for (int r = 0; r < 4; ++r)
            #pragma unroll
            for (int q = 0; q < 4; ++q) {
                int row = r * 16 + g * 4 + q;
                us[row][colA] = __float2bfloat16(silu_f(acc[r][0][q] + b1a));
                us[row][colB] = __float2bfloat16(silu_f(acc[r][1][q] + b1b));
            }
    }
    __syncthreads();

    zacc(acc);
    mfma_gemm<136>(us, 0, W2p, 4, w, lane, acc);
    {
        float b2a = b2[colA], b2b = b2[colB];
        #pragma unroll
        for (int r = 0; r < 4; ++r)
            #pragma unroll
            for (int q = 0; q < 4; ++q) {
                int row = r * 16 + g * 4 + q;
                int node = nb + row;
                if (node < N) {
                    outp[(size_t)node * 128 + colA] = acc[r][0][q] + b2a;
                    outp[(size_t)node * 128 + colB] = acc[r][1][q] + b2b;
                }
            }
    }
}

// =======================
extern "C" void kernel_launch(void* const* d_in, const int* in_sizes, int n_in,
                              void* d_out, int out_size, void* d_ws, size_t ws_size,
                              hipStream_t stream)
{
    const float* hin  = (const float*)d_in[0];
    const float* pos  = (const float*)d_in[1];
    const int*   ei   = (const int*)d_in[2];
    const float* embW = (const float*)d_in[3];
    const float* embb = (const float*)d_in[4];
    const float* mW1  = (const float*)d_in[5];
    const float* mb1  = (const float*)d_in[6];
    const float* mW2  = (const float*)d_in[7];
    const float* mb2  = (const float*)d_in[8];
    const float* cW1  = (const float*)d_in[9];
    const float* cb1  = (const float*)d_in[10];
    const float* cW2  = (const float*)d_in[11];
    const float* cb2  = (const float*)d_in[12];
    const float* nW1  = (const float*)d_in[13];
    const float* nb1  = (const float*)d_in[14];
    const float* nW2  = (const float*)d_in[15];
    const float* nb2  = (const float*)d_in[16];
    const float* oW1  = (const float*)d_in[17];
    const float* ob1  = (const float*)d_in[18];
    const float* oW2  = (const float*)d_in[19];
    const float* ob2  = (const float*)d_in[20];

    const int N = in_sizes[0] / 64;
    const int E = in_sizes[2] / 2;
    const int Etot = E + N;

    float* hbuf = (float*)d_ws;                                  // N*128 f32
    float* aggb = hbuf + (size_t)N * 128;                        // N*128 f32
    float* posb = aggb + (size_t)N * 128;                        // N*3
    float* pdel = posb + (size_t)N * 3;                          // N*3
    float* wnum = pdel + (size_t)N * 3;                          // N f32
    __hip_bfloat16* h16 = (__hip_bfloat16*)(wnum + N);           // N*128 bf16
    __hip_bfloat16* U16 = h16 + (size_t)N * 128;                 // N*128 bf16
    __hip_bfloat16* V16 = U16 + (size_t)N * 128;                 // N*128 bf16
    __hip_bfloat16* packed = V16 + (size_t)N * 128;              // 120*4096 bf16
    int* cnt  = (int*)(packed + 120 * 4096);                     // N
    int* soff = cnt + N;                                         // N
    int* part = soff + N;                                        // 64
    int* esrc = part + 64;                                       // Etot
    int* edst = esrc + Etot;                                     // Etot
    float* outp = (float*)d_out;

    // ---- weight repack descriptors
    PackArgs pa;
    int nm = 0; unsigned int poff = 0; int totalChunks = 0;
    auto addm = [&](const float* s, int kc) {
        pa.src[nm] = s; pa.doff[nm] = poff; pa.nchunk[nm] = kc;
        poff += (unsigned int)kc * 4096; totalChunks += kc; ++nm;
    };
    for (int l = 0; l < 4; ++l) {
        addm(mW1 + (size_t)l * 257 * 128, 8);
        addm(mW2 + (size_t)l * 128 * 128, 4);
        addm(cW1 + (size_t)l * 128 * 128, 4);
        addm(nW1 + (size_t)l * 256 * 128, 8);
        addm(nW2 + (size_t)l * 128 * 128, 4);
    }
    addm(oW1, 4);
    addm(oW2, 4);
    pa.nmat = nm;

    const unsigned int LSTRIDE = 28 * 4096;

    hipMemcpyAsync(posb, pos, (size_t)N * 3 * sizeof(float),
                   hipMemcpyDeviceToDevice, stream);
    repack_kernel<<<totalChunks, 256, 0, stream>>>(pa, packed);

    // ---- dst-sort edges (once, reused by all 4 layers)
    const int scanBlocks = (N + 4095) / 4096;
    hipMemsetAsync(cnt, 0, (size_t)N * sizeof(int), stream);
    hist_kernel<<<(Etot + 255) / 256, 256, 0, stream>>>(ei, cnt, E, N);
    scan_block_kernel<<<scanBlocks, 256, 0, stream>>>(cnt, soff, part, N);
    scan_part_kernel<<<1, 64, 0, stream>>>(part, scanBlocks);
    scan_add_kernel<<<scanBlocks, 256, 0, stream>>>(soff, part, N);
    scatter_kernel<<<(Etot + 255) / 256, 256, 0, stream>>>(ei, soff, esrc, edst, E, N);

    const int nodeBlocks32 = (N + 31) / 32;
    const int nodeBlocks64 = (N + 63) / 64;
    const int edgeBlocks   = (Etot + 63) / 64;

    embed_kernel<<<nodeBlocks32, 256, 0, stream>>>(hin, embW, embb, hbuf, h16, N);

    precompute_kernel<<<nodeBlocks64, 256, 0, stream>>>(
        h16, packed, packed + 12 * 4096,
        cb1, cW2, cb2, U16, V16, wnum, N);

    for (int l = 0; l < 4; ++l) {
        hipMemsetAsync(aggb, 0, (size_t)N * 128 * sizeof(float), stream);
        hipMemsetAsync(pdel, 0, (size_t)N * 3 * sizeof(float), stream);
        const __hip_bfloat16* lp = packed + (size_t)l * LSTRIDE;
        edge_kernel<<<edgeBlocks, 256, 0, stream>>>(
            U16, V16, wnum, posb, esrc, edst,
            mW1 + (size_t)l * 257 * 128 + 256 * 128, mb1 + l * 128,
            lp + 8 * 4096, mb2 + l * 128,
            aggb, pdel, Etot);
        node_mfma_kernel<<<nodeBlocks64, 256, 0, stream>>>(
            hbuf, h16, aggb, posb, pdel,
            lp + 16 * 4096, nb1 + l * 128,
            lp + 24 * 4096, nb2 + l * 128, N);
        if (l < 3) {
            const __hip_bfloat16* lpn = packed + (size_t)(l + 1) * LSTRIDE;
            precompute_kernel<<<nodeBlocks64, 256, 0, stream>>>(
                h16, lpn, lpn + 12 * 4096,
                cb1 + (l + 1) * 128, cW2 + (size_t)(l + 1) * 128, cb2 + (l + 1),
                U16, V16, wnum, N);
        }
    }
    out_mfma_kernel<<<nodeBlocks64, 256, 0, stream>>>(
        h16, packed + (size_t)4 * LSTRIDE, ob1,
        packed + (size_t)4 * LSTRIDE + 4 * 4096, ob2, outp, N);

    hipMemcpyAsync(outp + (size_t)N * 128, posb, (size_t)N * 3 * sizeof(float),
                   hipMemcpyDeviceToDevice, stream);
}